// Round 10
// baseline (1332.694 us; speedup 1.0000x reference)
//
#include <hip/hip_runtime.h>

#define ND 64        // feature dim
#define NR 8         // num edge types
#define NSLICE 8     // dst slices (XCD count)
#define SLICE_NODES 6272   // 196*32, multiple of 32; 8*6272 >= 50000
#define TPS 196      // tiles per slice (32 nodes each)
#define NTILE_AL 1568
#define CAPA 216064  // per-slice bucket capacity (mean 200704, ~35 sigma)
#define CAPB 1536    // per-tile bucket capacity (mean 1024, 16 sigma)

typedef __bf16 bf16x8 __attribute__((ext_vector_type(8)));
typedef float f32x4 __attribute__((ext_vector_type(4)));
typedef unsigned short us8 __attribute__((ext_vector_type(8)));

__device__ inline unsigned short bf16_rne(float f) {
    unsigned u = __float_as_uint(f);
    unsigned r = (u + 0x7FFFu + ((u >> 16) & 1u)) >> 16;
    return (unsigned short)r;
}
__device__ inline float bf16_to_f(unsigned short s) {
    return __uint_as_float(((unsigned)s) << 16);
}

// ---------------------------------------------------------------- zero ints
__global__ __launch_bounds__(256) void zeroi_kernel(int* __restrict__ p, int n) {
    int i = blockIdx.x * 256 + threadIdx.x;
    int stride = gridDim.x * 256;
    for (; i < n; i += stride) p[i] = 0;
}

// ---------------------------------------------------------------- A1: bucket edges into 8 dst-slices
// LDS-staged: count -> prefix -> scatter to LDS -> dense contiguous global runs
// (per 1024-edge batch, each slice window gets ~128 contiguous 8B entries).
__global__ __launch_bounds__(256) void bucket8_kernel(
    const int* __restrict__ src, const int* __restrict__ dst,
    const int* __restrict__ typ, int* __restrict__ bcur,
    uint2* __restrict__ bbufA, int nEdges)
{
    __shared__ uint2 outst[1024];
    __shared__ int lcnt[NSLICE];
    __shared__ int lbase[NSLICE];
    __shared__ int gbase[NSLICE];
    int tid = threadIdx.x;

    for (int base = blockIdx.x * 1024; base < nEdges; base += gridDim.x * 1024) {
        int bn = min(1024, nEdges - base);
        if (tid < NSLICE) lcnt[tid] = 0;
        __syncthreads();
        uint2 ent[4]; int eb[4], eo[4];
#pragma unroll
        for (int k = 0; k < 4; ++k) {
            int i = tid + k * 256;
            eb[k] = -1;
            if (i < bn) {
                int e = base + i;
                int d = dst[e];
                int s = d / SLICE_NODES;
                eb[k] = s;
                ent[k].x = (unsigned)src[e];
                ent[k].y = ((unsigned)s << 16) | ((unsigned)typ[e] << 13) |
                           (unsigned)(d - s * SLICE_NODES);
                eo[k] = atomicAdd(&lcnt[s], 1);
            }
        }
        __syncthreads();
        if (tid == 0) {
            int run = 0;
#pragma unroll
            for (int i = 0; i < NSLICE; ++i) { lbase[i] = run; run += lcnt[i]; }
        }
        if (tid < NSLICE && lcnt[tid] > 0) gbase[tid] = atomicAdd(&bcur[tid], lcnt[tid]);
        __syncthreads();
#pragma unroll
        for (int k = 0; k < 4; ++k)
            if (eb[k] >= 0) outst[lbase[eb[k]] + eo[k]] = ent[k];
        __syncthreads();
#pragma unroll
        for (int k = 0; k < 4; ++k) {
            int i = tid + k * 256;
            if (i < bn) {
                uint2 e = outst[i];
                int s = e.y >> 16;
                bbufA[(long)s * CAPA + gbase[s] + (i - lbase[s])] = e;
            }
        }
        __syncthreads();
    }
}

// ---------------------------------------------------------------- A2: per-slice re-bin into 196 node-tiles
// Same LDS staging; global writes are contiguous runs (~10 entries/bin/batch).
__global__ __launch_bounds__(256) void subbucket_kernel(
    const uint2* __restrict__ bbufA, const int* __restrict__ bcur,
    int* __restrict__ tilecur, uint2* __restrict__ bbufB)
{
    __shared__ uint2 outst[2048];
    __shared__ int lcnt[TPS];
    __shared__ int lbase[TPS];
    __shared__ int gbase[TPS];
    __shared__ int scanbuf[256];
    int tid = threadIdx.x;
    int slice = blockIdx.x & 7;
    int chunk = blockIdx.x >> 3;
    int nchunk = gridDim.x >> 3;
    int n = bcur[slice];
    const uint2* in = bbufA + (long)slice * CAPA;
    int per = (n + nchunk - 1) / nchunk;
    int beg = chunk * per;
    int end = min(beg + per, n);

    for (int b0 = beg; b0 < end; b0 += 2048) {
        int bn = min(2048, end - b0);
        if (tid < TPS) lcnt[tid] = 0;
        __syncthreads();
        uint2 ent[8]; int eb[8], eo[8];
#pragma unroll
        for (int k = 0; k < 8; ++k) {
            int i = tid + k * 256;
            eb[k] = -1;
            if (i < bn) {
                ent[k] = in[b0 + i];
                int bin = (ent[k].y & 8191u) >> 5;
                eb[k] = bin;
                eo[k] = atomicAdd(&lcnt[bin], 1);
            }
        }
        __syncthreads();
        // 256-wide Hillis-Steele scan over bins (196 used)
        int v = (tid < TPS) ? lcnt[tid] : 0;
        scanbuf[tid] = v;
        __syncthreads();
        int xs = v;
        for (int off = 1; off < 256; off <<= 1) {
            int y = (tid >= off) ? scanbuf[tid - off] : 0;
            __syncthreads();
            xs += y;
            scanbuf[tid] = xs;
            __syncthreads();
        }
        if (tid < TPS) {
            lbase[tid] = xs - v;
            if (v > 0) gbase[tid] = atomicAdd(&tilecur[slice * TPS + tid], v);
        }
        __syncthreads();
#pragma unroll
        for (int k = 0; k < 8; ++k)
            if (eb[k] >= 0) outst[lbase[eb[k]] + eo[k]] = ent[k];
        __syncthreads();
#pragma unroll
        for (int k = 0; k < 8; ++k) {
            int i = tid + k * 256;
            if (i < bn) {
                uint2 e = outst[i];
                int bin = (e.y & 8191u) >> 5;
                bbufB[(long)(slice * TPS + bin) * CAPB + gbase[bin] + (i - lbase[bin])] = e;
            }
        }
        __syncthreads();
    }
}

// ---------------------------------------------------------------- weight convert+transpose (relation W)
__global__ __launch_bounds__(256) void convw_kernel(
    const float* __restrict__ W, unsigned short* __restrict__ wt)
{
    int idx = blockIdx.x * 256 + threadIdx.x;
    if (idx >= 64 * 512) return;
    int o = idx >> 9, k = idx & 511;
    wt[idx] = bf16_rne(W[(long)k * 64 + o]);
}

// ---------------------------------------------------------------- MLP weight convert+transpose
__global__ __launch_bounds__(256) void convm_kernel(
    const float* __restrict__ m, unsigned short* __restrict__ wmt)
{
    int idx = blockIdx.x * 256 + threadIdx.x;
    if (idx >= 64 * 64) return;
    int o = idx >> 6, k = idx & 63;
    wmt[idx] = bf16_rne(m[k * 64 + o]);
}

// ---------------------------------------------------------------- x -> bf16
__global__ __launch_bounds__(256) void convx_kernel(
    const float4* __restrict__ x, unsigned short* __restrict__ xb, int n8)
{
    int i = blockIdx.x * 256 + threadIdx.x;
    if (i >= n8) return;
    float4 v0 = x[i * 2], v1 = x[i * 2 + 1];
    us8 o;
    o[0] = bf16_rne(v0.x); o[1] = bf16_rne(v0.y);
    o[2] = bf16_rne(v0.z); o[3] = bf16_rne(v0.w);
    o[4] = bf16_rne(v1.x); o[5] = bf16_rne(v1.y);
    o[6] = bf16_rne(v1.z); o[7] = bf16_rne(v1.w);
    *(us8*)(xb + (long)i * 8) = o;
}

// ---------------------------------------------------------------- B: per-tile LDS aggregation
// Block = one 32-node dst tile. LDS ag[8][32][64] f32 (64KB). 16-lane groups
// stream the tile's edges; lane owns 4 features; LDS atomic accumulate.
// Writeout coalesced bf16. Replaces hist/scan/permute/gather.
__global__ __launch_bounds__(256) void aggregate_kernel(
    const unsigned short* __restrict__ xb, const uint2* __restrict__ bbufB,
    const int* __restrict__ tilecur, unsigned short* __restrict__ agbf, int nNodes)
{
    __shared__ float ag[NR][32][ND];   // 64 KB
    int tile = blockIdx.x;
    int tid = threadIdx.x;

    float4* agz = (float4*)&ag[0][0][0];
#pragma unroll
    for (int k = 0; k < 16; ++k)
        agz[tid + k * 256] = make_float4(0.f, 0.f, 0.f, 0.f);
    __syncthreads();

    int n = tilecur[tile];
    const uint2* buf = bbufB + (long)tile * CAPB;
    int grp = tid >> 4;      // 16 groups of 16 lanes
    int fl = tid & 15;       // lane's 4-feature slice

#pragma unroll 2
    for (int i = grp; i < n; i += 16) {
        uint2 e = buf[i];
        int r = (e.y >> 13) & 7;
        int nl = e.y & 31;
        ushort4 v = *(const ushort4*)(xb + (long)e.x * ND + fl * 4);
        atomicAdd(&ag[r][nl][fl * 4 + 0], bf16_to_f(v.x));
        atomicAdd(&ag[r][nl][fl * 4 + 1], bf16_to_f(v.y));
        atomicAdd(&ag[r][nl][fl * 4 + 2], bf16_to_f(v.z));
        atomicAdd(&ag[r][nl][fl * 4 + 3], bf16_to_f(v.w));
    }
    __syncthreads();

    // writeout: 32 nodes x 512 bf16 = 2048 us8-chunks; 8 per thread, coalesced
    int nbase = tile * 32;
#pragma unroll
    for (int k = 0; k < 8; ++k) {
        int c = tid + k * 256;
        int nl = c >> 6;
        int node = nbase + nl;
        if (node < nNodes) {
            int rf = (c & 63) * 8;           // r*64 + f0
            int r = rf >> 6, f0 = rf & 63;
            us8 o;
#pragma unroll
            for (int j = 0; j < 8; ++j) o[j] = bf16_rne(ag[r][nl][f0 + j]);
            *(us8*)(agbf + (long)node * 512 + rf) = o;
        }
    }
}

// ---------------------------------------------------------------- MFMA einsum
// msgs[M=nodes, 64] = A[M, 512] @ Wt^T   (A = agbf, Wt = [64][512] bf16)
__global__ __launch_bounds__(256) void einsum_kernel(
    const unsigned short* __restrict__ agbf, const unsigned short* __restrict__ wt,
    float* __restrict__ msgs, int nNodes)
{
    int wid = blockIdx.x * 4 + (threadIdx.x >> 6);
    int lane = threadIdx.x & 63;
    int nbase = wid * 32;
    if (nbase >= nNodes) return;
    int r16 = lane & 15;
    int kg  = lane >> 4;

    f32x4 acc[2][4];
#pragma unroll
    for (int m = 0; m < 2; ++m)
#pragma unroll
        for (int j = 0; j < 4; ++j) acc[m][j] = (f32x4){0.f, 0.f, 0.f, 0.f};

    int n0 = nbase + r16;      if (n0 >= nNodes) n0 = nNodes - 1;
    int n1 = nbase + 16 + r16; if (n1 >= nNodes) n1 = nNodes - 1;
    const unsigned short* a0p = agbf + (long)n0 * 512 + kg * 8;
    const unsigned short* a1p = agbf + (long)n1 * 512 + kg * 8;
    const unsigned short* bp  = wt + (long)r16 * 512 + kg * 8;

#pragma unroll 4
    for (int kk = 0; kk < 16; ++kk) {
        bf16x8 a0 = *(const bf16x8*)(a0p + kk * 32);
        bf16x8 a1 = *(const bf16x8*)(a1p + kk * 32);
#pragma unroll
        for (int j = 0; j < 4; ++j) {
            bf16x8 b = *(const bf16x8*)(bp + (long)j * 16 * 512 + kk * 32);
            acc[0][j] = __builtin_amdgcn_mfma_f32_16x16x32_bf16(a0, b, acc[0][j], 0, 0, 0);
            acc[1][j] = __builtin_amdgcn_mfma_f32_16x16x32_bf16(a1, b, acc[1][j], 0, 0, 0);
        }
    }

    // C layout (verified m89): col = lane&15, row = (lane>>4)*4 + reg
#pragma unroll
    for (int m = 0; m < 2; ++m) {
#pragma unroll
        for (int reg = 0; reg < 4; ++reg) {
            int row = nbase + m * 16 + kg * 4 + reg;
            if (row < nNodes) {
#pragma unroll
                for (int j = 0; j < 4; ++j)
                    msgs[(long)row * ND + j * 16 + r16] = acc[m][j][reg];
            }
        }
    }
}

// ---------------------------------------------------------------- MFMA MLP stage A
__global__ __launch_bounds__(256) void mlpA_kernel(
    const float* __restrict__ xin, const float* __restrict__ msgs,
    const float* __restrict__ eps, const unsigned short* __restrict__ wm1t,
    const float* __restrict__ mb1, unsigned short* __restrict__ tout, int nNodes)
{
    int wid = blockIdx.x * 4 + (threadIdx.x >> 6);
    int lane = threadIdx.x & 63;
    int nbase = wid * 32;
    if (nbase >= nNodes) return;
    int r16 = lane & 15;
    int kg  = lane >> 4;
    float epsv = 1.0f + eps[0];

    int n0 = nbase + r16;      if (n0 >= nNodes) n0 = nNodes - 1;
    int n1 = nbase + 16 + r16; if (n1 >= nNodes) n1 = nNodes - 1;

    bf16x8 afr[2][2];
#pragma unroll
    for (int m = 0; m < 2; ++m) {
        long nrow = (m == 0) ? n0 : n1;
#pragma unroll
        for (int kk = 0; kk < 2; ++kk) {
            long base = nrow * ND + kg * 8 + kk * 32;
            float4 x0 = *(const float4*)(xin + base);
            float4 x1 = *(const float4*)(xin + base + 4);
            float4 m0 = *(const float4*)(msgs + base);
            float4 m1 = *(const float4*)(msgs + base + 4);
            us8 u;
            u[0] = bf16_rne(fmaf(epsv, x0.x, m0.x));
            u[1] = bf16_rne(fmaf(epsv, x0.y, m0.y));
            u[2] = bf16_rne(fmaf(epsv, x0.z, m0.z));
            u[3] = bf16_rne(fmaf(epsv, x0.w, m0.w));
            u[4] = bf16_rne(fmaf(epsv, x1.x, m1.x));
            u[5] = bf16_rne(fmaf(epsv, x1.y, m1.y));
            u[6] = bf16_rne(fmaf(epsv, x1.z, m1.z));
            u[7] = bf16_rne(fmaf(epsv, x1.w, m1.w));
            afr[m][kk] = __builtin_bit_cast(bf16x8, u);
        }
    }

    f32x4 acc[2][4];
#pragma unroll
    for (int m = 0; m < 2; ++m)
#pragma unroll
        for (int j = 0; j < 4; ++j) acc[m][j] = (f32x4){0.f, 0.f, 0.f, 0.f};

#pragma unroll
    for (int kk = 0; kk < 2; ++kk) {
#pragma unroll
        for (int j = 0; j < 4; ++j) {
            bf16x8 b = *(const bf16x8*)(wm1t + (long)(j * 16 + r16) * ND + kg * 8 + kk * 32);
            acc[0][j] = __builtin_amdgcn_mfma_f32_16x16x32_bf16(afr[0][kk], b, acc[0][j], 0, 0, 0);
            acc[1][j] = __builtin_amdgcn_mfma_f32_16x16x32_bf16(afr[1][kk], b, acc[1][j], 0, 0, 0);
        }
    }

#pragma unroll
    for (int m = 0; m < 2; ++m) {
#pragma unroll
        for (int reg = 0; reg < 4; ++reg) {
            int row = nbase + m * 16 + kg * 4 + reg;
            if (row < nNodes) {
#pragma unroll
                for (int j = 0; j < 4; ++j) {
                    int col = j * 16 + r16;
                    float v = acc[m][j][reg] + mb1[col];
                    v = fmaxf(v, 0.f);
                    tout[(long)row * ND + col] = bf16_rne(v);
                }
            }
        }
    }
}

// ---------------------------------------------------------------- MFMA MLP stage B
__global__ __launch_bounds__(256) void mlpB_kernel(
    const unsigned short* __restrict__ tin, const unsigned short* __restrict__ wm2t,
    const float* __restrict__ mb2, const float* __restrict__ bias,
    float* __restrict__ out, unsigned short* __restrict__ out_bf, int nNodes)
{
    int wid = blockIdx.x * 4 + (threadIdx.x >> 6);
    int lane = threadIdx.x & 63;
    int nbase = wid * 32;
    if (nbase >= nNodes) return;
    int r16 = lane & 15;
    int kg  = lane >> 4;

    int n0 = nbase + r16;      if (n0 >= nNodes) n0 = nNodes - 1;
    int n1 = nbase + 16 + r16; if (n1 >= nNodes) n1 = nNodes - 1;
    const unsigned short* a0p = tin + (long)n0 * ND + kg * 8;
    const unsigned short* a1p = tin + (long)n1 * ND + kg * 8;

    f32x4 acc[2][4];
#pragma unroll
    for (int m = 0; m < 2; ++m)
#pragma unroll
        for (int j = 0; j < 4; ++j) acc[m][j] = (f32x4){0.f, 0.f, 0.f, 0.f};

#pragma unroll
    for (int kk = 0; kk < 2; ++kk) {
        bf16x8 a0 = *(const bf16x8*)(a0p + kk * 32);
        bf16x8 a1 = *(const bf16x8*)(a1p + kk * 32);
#pragma unroll
        for (int j = 0; j < 4; ++j) {
            bf16x8 b = *(const bf16x8*)(wm2t + (long)(j * 16 + r16) * ND + kg * 8 + kk * 32);
            acc[0][j] = __builtin_amdgcn_mfma_f32_16x16x32_bf16(a0, b, acc[0][j], 0, 0, 0);
            acc[1][j] = __builtin_amdgcn_mfma_f32_16x16x32_bf16(a1, b, acc[1][j], 0, 0, 0);
        }
    }

#pragma unroll
    for (int m = 0; m < 2; ++m) {
#pragma unroll
        for (int reg = 0; reg < 4; ++reg) {
            int row = nbase + m * 16 + kg * 4 + reg;
            if (row < nNodes) {
#pragma unroll
                for (int j = 0; j < 4; ++j) {
                    int col = j * 16 + r16;
                    float v = acc[m][j][reg] + mb2[col] + bias[col];
                    out[(long)row * ND + col] = v;
                    if (out_bf != nullptr)
                        out_bf[(long)row * ND + col] = bf16_rne(v);
                }
            }
        }
    }
}

// ---------------------------------------------------------------- launch
extern "C" void kernel_launch(void* const* d_in, const int* in_sizes, int n_in,
                              void* d_out, int out_size, void* d_ws, size_t ws_size,
                              hipStream_t stream) {
    const float* x    = (const float*)d_in[0];
    const int* esrc   = (const int*)d_in[1];
    const int* edst   = (const int*)d_in[2];
    const int* etyp   = (const int*)d_in[3];

    const float* W1   = (const float*)d_in[4];
    const float* b1   = (const float*)d_in[5];
    const float* e1   = (const float*)d_in[6];
    const float* m1w1 = (const float*)d_in[7];
    const float* m1b1 = (const float*)d_in[8];
    const float* m1w2 = (const float*)d_in[9];
    const float* m1b2 = (const float*)d_in[10];

    const float* W2   = (const float*)d_in[11];
    const float* b2   = (const float*)d_in[12];
    const float* e2   = (const float*)d_in[13];
    const float* m2w1 = (const float*)d_in[14];
    const float* m2b1 = (const float*)d_in[15];
    const float* m2w2 = (const float*)d_in[16];
    const float* m2b2 = (const float*)d_in[17];

    int nNodes = in_sizes[0] / ND;   // 50000
    int nEdges = in_sizes[1];        // 1600000
    int ntiles = (nNodes + 31) / 32; // 1563

    // ---- workspace layout (~104 MB)
    unsigned short* agbf = (unsigned short*)d_ws;                 // N*512 bf16 = 51.2MB
    float* msgs   = (float*)(agbf + (long)nNodes * 512);          // N*64 f32 = 12.8MB
    unsigned short* xhbf = (unsigned short*)(msgs + (long)nNodes * ND); // 6.4MB
    unsigned short* wt1  = xhbf + (long)nNodes * ND;
    unsigned short* wt2  = wt1 + 64 * 512;
    unsigned short* wm11 = wt2 + 64 * 512;
    unsigned short* wm12 = wm11 + 64 * 64;
    unsigned short* wm21 = wm12 + 64 * 64;
    unsigned short* wm22 = wm21 + 64 * 64;
    uint2* bbufA  = (uint2*)(wm22 + 64 * 64);                     // 8*CAPA*8B = 13.8MB
    uint2* bbufB  = bbufA + (long)NSLICE * CAPA;                  // 1568*1536*8B = 19.3MB
    int* cnts     = (int*)(bbufB + (long)NTILE_AL * CAPB);        // 8 + 1568
    int* bcur     = cnts;
    int* tilecur  = cnts + NSLICE;
    unsigned short* tbuf = (unsigned short*)bbufA;  // alias: bbufA dead after A2
    float* h    = (float*)d_out;   // layer-1 fp32 h aliases d_out
    float* outp = (float*)d_out;

    int esgrid = (ntiles * 32 / 32 + 3) / 4;   // = ceil(nNodes/32)/4 waves-blocks
    esgrid = ((nNodes + 31) / 32 + 3) / 4;
    int n8 = nNodes * ND / 8;

    // ---- build tile buckets once (graph shared by both layers)
    zeroi_kernel<<<7, 256, 0, stream>>>(cnts, NSLICE + NTILE_AL);
    bucket8_kernel<<<782, 256, 0, stream>>>(esrc, edst, etyp, bcur, bbufA, nEdges);
    subbucket_kernel<<<320, 256, 0, stream>>>(bbufA, bcur, tilecur, bbufB);

    // ---- weight + x converts
    convw_kernel<<<128, 256, 0, stream>>>(W1, wt1);
    convw_kernel<<<128, 256, 0, stream>>>(W2, wt2);
    convm_kernel<<<16, 256, 0, stream>>>(m1w1, wm11);
    convm_kernel<<<16, 256, 0, stream>>>(m1w2, wm12);
    convm_kernel<<<16, 256, 0, stream>>>(m2w1, wm21);
    convm_kernel<<<16, 256, 0, stream>>>(m2w2, wm22);
    convx_kernel<<<(n8 + 255) / 256, 256, 0, stream>>>((const float4*)x, xhbf, n8);

    // ---- layer 1
    aggregate_kernel<<<ntiles, 256, 0, stream>>>(xhbf, bbufB, tilecur, agbf, nNodes);
    einsum_kernel<<<esgrid, 256, 0, stream>>>(agbf, wt1, msgs, nNodes);
    mlpA_kernel<<<esgrid, 256, 0, stream>>>(x, msgs, e1, wm11, m1b1, tbuf, nNodes);
    mlpB_kernel<<<esgrid, 256, 0, stream>>>(tbuf, wm12, m1b2, b1, h, xhbf, nNodes);

    // ---- layer 2
    aggregate_kernel<<<ntiles, 256, 0, stream>>>(xhbf, bbufB, tilecur, agbf, nNodes);
    einsum_kernel<<<esgrid, 256, 0, stream>>>(agbf, wt2, msgs, nNodes);
    mlpA_kernel<<<esgrid, 256, 0, stream>>>(h, msgs, e2, wm21, m2b1, tbuf, nNodes);
    mlpB_kernel<<<esgrid, 256, 0, stream>>>(tbuf, wm22, m2b2, b2, outp, nullptr, nNodes);
}